// Round 1
// baseline (56.279 us; speedup 1.0000x reference)
//
#include <hip/hip_runtime.h>
#include <hip/hip_bf16.h>
#include <math.h>

// Problem: B=64, C=128, H=64, W=64, HW=4096
// out  : (B,C,H,W) f32  = 33,554,432 elems at d_out[0]
// logdet: (B,)      f32  = 64 elems at d_out[33554432]
//
// Key algebraic reduction: pool[b,l] = mean_o( sum_c w[o,c]*mask*x ) + mean(bias)
//                                    = sum_c wbar[c]*mask[c,l]*x[b,c,l] + bbar
// so the 128x128 channel mix never needs to be materialized.

#define EPS 1e-5f
#define NC 128
#define NHW 4096
#define NB 64
#define LT 64            // pixels per block tile
#define NLT (NHW / LT)   // 64 l-tiles... wait: 4096/64 = 64

// ws layout (floats):
//  [0..127]   wbar
//  [128..255] s_sig
//  [256]      bbar
//  [257]      logdet_const
//  [512 .. 512 + NB*NLT) per-block log-g partials

__global__ __launch_bounds__(128) void prep_kernel(const float* __restrict__ w,
                                                   const float* __restrict__ bias,
                                                   const float* __restrict__ s,
                                                   float* __restrict__ ws) {
    __shared__ float red[NC];
    const int c = threadIdx.x;  // 128 threads
    // wbar[c] = (1/C) sum_o w[o*C + c]
    float acc = 0.f;
    for (int o = 0; o < NC; ++o) acc += w[o * NC + c];
    ws[c] = acc * (1.f / NC);
    // s_sig
    const float sv = s[c];
    const float ssig = 1.f / (1.f + expf(-sv)) + EPS;
    ws[NC + c] = ssig;

    // bbar = mean(bias)
    red[c] = bias[c];
    __syncthreads();
    if (c == 0) {
        double sb = 0.0;
        for (int i = 0; i < NC; ++i) sb += (double)red[i];
        ws[256] = (float)(sb / NC);
    }
    __syncthreads();
    red[c] = logf(ssig);
    __syncthreads();
    if (c == 0) {
        double sl = 0.0;
        for (int i = 0; i < NC; ++i) sl += (double)red[i];
        // logdet const term: B * sum_{c,l} log(s_sig[c]) * mask[c,l]
        //                  = B * (HW/2) * sum_c log(s_sig[c])
        ws[257] = (float)((double)NB * (double)(NHW / 2) * sl);
    }
}

__global__ __launch_bounds__(256) void main_kernel(const float* __restrict__ x,
                                                   const float* __restrict__ ws,
                                                   const float* __restrict__ offp,
                                                   float* __restrict__ out,
                                                   float* __restrict__ partials) {
    __shared__ float xs[NC][LT];   // 32 KiB
    __shared__ float pp[4][LT];
    __shared__ float gsh[LT];

    const int tid = threadIdx.x;
    const int lt  = blockIdx.x;            // l-tile index, 0..NLT-1
    const int b   = blockIdx.y;            // batch, 0..63
    const int l0  = lt * LT;               // even
    const size_t xbase = (size_t)b * (NC * NHW) + l0;

    // ---- load 128 x 64 f32 tile into LDS (float4, coalesced) ----
    // 128*64/4 = 2048 float4s; 256 threads -> 8 iters
#pragma unroll
    for (int it = 0; it < 8; ++it) {
        const int idx = it * 256 + tid;
        const int c = idx >> 4;       // 0..127
        const int j = idx & 15;       // 0..15 (float4 within row)
        const float4 v = *reinterpret_cast<const float4*>(x + xbase + (size_t)c * NHW + j * 4);
        *reinterpret_cast<float4*>(&xs[c][j * 4]) = v;
    }
    __syncthreads();

    // ---- pool partial: lane l = tid&63, c-quarter q = tid>>6 ----
    const int l = tid & 63;
    const int q = tid >> 6;
    {
        float acc = 0.f;
#pragma unroll
        for (int cc = 0; cc < 32; ++cc) {
            const int c = q * 32 + cc;
            // mask[c, l0+l] = (c + l0 + l) & 1 = (c + l) & 1  (l0 even)
            const float m = (float)((c + l) & 1);
            acc += m * ws[c] * xs[c][l];
        }
        pp[q][l] = acc;
    }
    __syncthreads();

    float g = 0.f;
    if (tid < 64) {
        const float pool = pp[0][l] + pp[1][l] + pp[2][l] + pp[3][l] + ws[256];
        const float t = pool + offp[0];
        g = 1.f / (1.f + __expf(-t)) + EPS;
        gsh[l] = g;
    }
    __syncthreads();

    // ---- per-block sum of log(g) over the 64 pixels (wave 0 only) ----
    if (tid < 64) {
        float lg = __logf(g);
#pragma unroll
        for (int off = 32; off > 0; off >>= 1) lg += __shfl_down(lg, off);
        if (tid == 0) partials[b * gridDim.x + lt] = lg;
    }

    // ---- output: out = x * ((c+l)&1 ? s_sig[c] : g[l]) ----
    const float* __restrict__ ssig = ws + NC;
#pragma unroll
    for (int it = 0; it < 8; ++it) {
        const int idx = it * 256 + tid;
        const int c = idx >> 4;
        const int j = idx & 15;
        const float sc = ssig[c];
        const float4 v = *reinterpret_cast<const float4*>(&xs[c][j * 4]);
        // element e at pixel l0 + j*4 + e; parity = (c + e) & 1 (l0, j*4 even)
        float4 o;
        const float g0 = gsh[j * 4 + 0];
        const float g1 = gsh[j * 4 + 1];
        const float g2 = gsh[j * 4 + 2];
        const float g3 = gsh[j * 4 + 3];
        if (c & 1) {
            o.x = v.x * sc;  o.y = v.y * g1;  o.z = v.z * sc;  o.w = v.w * g3;
        } else {
            o.x = v.x * g0;  o.y = v.y * sc;  o.z = v.z * g2;  o.w = v.w * sc;
        }
        *reinterpret_cast<float4*>(out + xbase + (size_t)c * NHW + j * 4) = o;
    }
}

__global__ __launch_bounds__(64) void fin_kernel(const float* __restrict__ partials,
                                                 const float* __restrict__ ws,
                                                 float* __restrict__ logdet,
                                                 int nlt) {
    const int b = blockIdx.x;
    const int t = threadIdx.x;  // 64 threads
    float v = (t < nlt) ? partials[b * nlt + t] : 0.f;
#pragma unroll
    for (int off = 32; off > 0; off >>= 1) v += __shfl_down(v, off);
    if (t == 0) logdet[b] = 64.f * v + ws[257];  // (C//2) = 64
}

extern "C" void kernel_launch(void* const* d_in, const int* in_sizes, int n_in,
                              void* d_out, int out_size, void* d_ws, size_t ws_size,
                              hipStream_t stream) {
    const float* x    = (const float*)d_in[0];
    const float* w    = (const float*)d_in[1];
    const float* bias = (const float*)d_in[2];
    const float* s    = (const float*)d_in[3];
    const float* offp = (const float*)d_in[4];

    float* out = (float*)d_out;
    float* logdet = out + (size_t)NB * NC * NHW;

    float* ws = (float*)d_ws;
    float* partials = ws + 512;

    const int nlt = NHW / LT;  // 64 l-tiles of 64 pixels

    prep_kernel<<<1, 128, 0, stream>>>(w, bias, s, ws);
    main_kernel<<<dim3(nlt, NB), 256, 0, stream>>>(x, ws, offp, out, partials);
    fin_kernel<<<NB, 64, 0, stream>>>(partials, ws, logdet, nlt);
}

// Round 2
// 55.684 us; speedup vs baseline: 1.0107x; 1.0107x over previous
//
#include <hip/hip_runtime.h>
#include <hip/hip_bf16.h>
#include <math.h>

// Problem: B=64, C=128, H=64, W=64, HW=4096
// out   : (B,C,H,W) f32  = 33,554,432 elems at d_out[0]
// logdet: (B,)      f32  = 64 elems at d_out[33554432]
//
// Algebraic reduction: pool[b,l] = sum_c wbar[c]*mask[c,l]*x[b,c,l] + bbar
// with wbar[c] = mean_o w[o,c], bbar = mean(bias). The 128x128 channel mix
// is never materialized.
//
// main_kernel: x held in registers (8 float4/thread), pool reduced via
// 2x shfl_xor + 1KiB LDS exchange, single __syncthreads, then scale+store.

#define EPS 1e-5f
#define NC 128
#define NHW 4096
#define NB 64
#define LT 64            // pixels per block tile
#define NLT (NHW / LT)

// ws layout (floats):
//  [0..127]   wbar
//  [128..255] s_sig
//  [256]      bbar
//  [257]      logdet_const
//  [512 .. 512 + NB*NLT) per-block log-g partials

__global__ __launch_bounds__(128) void prep_kernel(const float* __restrict__ w,
                                                   const float* __restrict__ bias,
                                                   const float* __restrict__ s,
                                                   float* __restrict__ ws) {
    __shared__ float red[NC];
    const int c = threadIdx.x;  // 128 threads
    float acc = 0.f;
    for (int o = 0; o < NC; ++o) acc += w[o * NC + c];
    ws[c] = acc * (1.f / NC);
    const float sv = s[c];
    const float ssig = 1.f / (1.f + expf(-sv)) + EPS;
    ws[NC + c] = ssig;

    red[c] = bias[c];
    __syncthreads();
    if (c == 0) {
        double sb = 0.0;
        for (int i = 0; i < NC; ++i) sb += (double)red[i];
        ws[256] = (float)(sb / NC);
    }
    __syncthreads();
    red[c] = logf(ssig);
    __syncthreads();
    if (c == 0) {
        double sl = 0.0;
        for (int i = 0; i < NC; ++i) sl += (double)red[i];
        ws[257] = (float)((double)NB * (double)(NHW / 2) * sl);
    }
}

__global__ __launch_bounds__(256) void main_kernel(const float* __restrict__ x,
                                                   const float* __restrict__ ws,
                                                   const float* __restrict__ offp,
                                                   float* __restrict__ out,
                                                   float* __restrict__ partials) {
    __shared__ float4 pp[4][16];   // 1 KiB: per-wave pool partials

    const int tid  = threadIdx.x;
    const int j    = tid & 15;     // pixel-quad index: pixels l0 + 4j .. 4j+3
    const int cg   = tid >> 4;     // channel group 0..15 (8 channels each)
    const int wave = tid >> 6;
    const int lane = tid & 63;

    const int lt = blockIdx.x;     // l-tile 0..63
    const int b  = blockIdx.y;     // batch
    const int l0 = lt * LT;        // multiple of 64 (even)

    const size_t base = (size_t)b * (NC * NHW) + (size_t)(cg * 8) * NHW + l0 + j * 4;
    const float* __restrict__ xp = x + base;

    // ---- load 8 float4 into registers (4x 256B contiguous segments / wave) ----
    float4 v[8];
#pragma unroll
    for (int k = 0; k < 8; ++k)
        v[k] = *reinterpret_cast<const float4*>(xp + (size_t)k * NHW);

    // ---- per-thread pool partial over its 8 channels ----
    // pool[l] = sum_c wbar[c] * ((c+l)&1) * x[c,l]; element e parity = (c+e)&1
    float4 acc = make_float4(0.f, 0.f, 0.f, 0.f);
#pragma unroll
    for (int k = 0; k < 8; ++k) {
        const int c = cg * 8 + k;
        const float wb = ws[c];
        if (c & 1) { acc.x += wb * v[k].x; acc.z += wb * v[k].z; }
        else       { acc.y += wb * v[k].y; acc.w += wb * v[k].w; }
    }

    // ---- reduce over the 4 channel-groups within this wave (lanes ^16, ^32) ----
#pragma unroll
    for (int off = 16; off <= 32; off <<= 1) {
        acc.x += __shfl_xor(acc.x, off);
        acc.y += __shfl_xor(acc.y, off);
        acc.z += __shfl_xor(acc.z, off);
        acc.w += __shfl_xor(acc.w, off);
    }
    if (lane < 16) pp[wave][j] = acc;   // lane==j for lane<16
    __syncthreads();

    // ---- final pool + gate (computed redundantly per thread; VALU is idle) ----
    const float4 p0 = pp[0][j], p1 = pp[1][j], p2 = pp[2][j], p3 = pp[3][j];
    const float cst = ws[256] + offp[0];
    float4 g;
    g.x = 1.f / (1.f + __expf(-(p0.x + p1.x + p2.x + p3.x + cst))) + EPS;
    g.y = 1.f / (1.f + __expf(-(p0.y + p1.y + p2.y + p3.y + cst))) + EPS;
    g.z = 1.f / (1.f + __expf(-(p0.z + p1.z + p2.z + p3.z + cst))) + EPS;
    g.w = 1.f / (1.f + __expf(-(p0.w + p1.w + p2.w + p3.w + cst))) + EPS;

    // ---- per-block sum of log(g) over the 64 pixels (wave 0, all lanes active) ----
    if (wave == 0) {
        float slg = (lane < 16)
                  ? (__logf(g.x) + __logf(g.y) + __logf(g.z) + __logf(g.w))
                  : 0.f;
#pragma unroll
        for (int off = 32; off > 0; off >>= 1) slg += __shfl_down(slg, off);
        if (lane == 0) partials[b * gridDim.x + lt] = slg;
    }

    // ---- scale registers and store: out = x * ((c+e)&1 ? s_sig[c] : g[e]) ----
    const float* __restrict__ ssig = ws + NC;
    float* __restrict__ op = out + base;
#pragma unroll
    for (int k = 0; k < 8; ++k) {
        const int c = cg * 8 + k;
        const float sc = ssig[c];
        float4 o;
        if (c & 1) { o.x = v[k].x * sc;  o.y = v[k].y * g.y;
                     o.z = v[k].z * sc;  o.w = v[k].w * g.w; }
        else       { o.x = v[k].x * g.x; o.y = v[k].y * sc;
                     o.z = v[k].z * g.z; o.w = v[k].w * sc; }
        *reinterpret_cast<float4*>(op + (size_t)k * NHW) = o;
    }
}

__global__ __launch_bounds__(64) void fin_kernel(const float* __restrict__ partials,
                                                 const float* __restrict__ ws,
                                                 float* __restrict__ logdet,
                                                 int nlt) {
    const int b = blockIdx.x;
    const int t = threadIdx.x;  // 64 threads
    float v = (t < nlt) ? partials[b * nlt + t] : 0.f;
#pragma unroll
    for (int off = 32; off > 0; off >>= 1) v += __shfl_down(v, off);
    if (t == 0) logdet[b] = 64.f * v + ws[257];  // (C//2) = 64
}

extern "C" void kernel_launch(void* const* d_in, const int* in_sizes, int n_in,
                              void* d_out, int out_size, void* d_ws, size_t ws_size,
                              hipStream_t stream) {
    const float* x    = (const float*)d_in[0];
    const float* w    = (const float*)d_in[1];
    const float* bias = (const float*)d_in[2];
    const float* s    = (const float*)d_in[3];
    const float* offp = (const float*)d_in[4];

    float* out = (float*)d_out;
    float* logdet = out + (size_t)NB * NC * NHW;

    float* ws = (float*)d_ws;
    float* partials = ws + 512;

    const int nlt = NHW / LT;

    prep_kernel<<<1, 128, 0, stream>>>(w, bias, s, ws);
    main_kernel<<<dim3(nlt, NB), 256, 0, stream>>>(x, ws, offp, out, partials);
    fin_kernel<<<NB, 64, 0, stream>>>(partials, ws, logdet, nlt);
}

// Round 3
// 52.089 us; speedup vs baseline: 1.0804x; 1.0690x over previous
//
#include <hip/hip_runtime.h>
#include <hip/hip_bf16.h>
#include <math.h>

// Problem: B=64, C=128, H=64, W=64, HW=4096
// out   : (B,C,H,W) f32  = 33,554,432 elems at d_out[0]
// logdet: (B,)      f32  = 64 elems at d_out[33554432]
//
// Algebraic reduction: pool[b,l] = sum_c wbar[c]*mask[c,l]*x[b,c,l] + bbar
// with wbar[c] = mean_o w[o,c], bbar = mean(bias). The 128x128 channel mix
// is never materialized.
//
// Round-3 change: NON-TEMPORAL stores for `out` (write-once stream). In
// steady state x(128MB)+out(128MB) exactly fills the 256MB Infinity Cache;
// allocating out evicts half of x each replay (FETCH_SIZE showed exactly
// x/2). nt stores keep x L3-resident -> HBM read traffic ~0.

#define EPS 1e-5f
#define NC 128
#define NHW 4096
#define NB 64
#define LT 64            // pixels per block tile
#define NLT (NHW / LT)

typedef __attribute__((ext_vector_type(4))) float f4;

// ws layout (floats):
//  [0..127]   wbar
//  [128..255] s_sig
//  [256]      bbar
//  [257]      logdet_const
//  [512 .. 512 + NB*NLT) per-block log-g partials

__global__ __launch_bounds__(128) void prep_kernel(const float* __restrict__ w,
                                                   const float* __restrict__ bias,
                                                   const float* __restrict__ s,
                                                   float* __restrict__ ws) {
    __shared__ float red[NC];
    const int c = threadIdx.x;  // 128 threads
    // wbar[c] = (1/C) sum_o w[o*C + c]; 8 independent partial accumulators
    float a0 = 0.f, a1 = 0.f, a2 = 0.f, a3 = 0.f;
    float a4 = 0.f, a5 = 0.f, a6 = 0.f, a7 = 0.f;
#pragma unroll
    for (int o = 0; o < NC; o += 8) {
        a0 += w[(o + 0) * NC + c];
        a1 += w[(o + 1) * NC + c];
        a2 += w[(o + 2) * NC + c];
        a3 += w[(o + 3) * NC + c];
        a4 += w[(o + 4) * NC + c];
        a5 += w[(o + 5) * NC + c];
        a6 += w[(o + 6) * NC + c];
        a7 += w[(o + 7) * NC + c];
    }
    ws[c] = (((a0 + a1) + (a2 + a3)) + ((a4 + a5) + (a6 + a7))) * (1.f / NC);

    const float sv = s[c];
    const float ssig = 1.f / (1.f + expf(-sv)) + EPS;
    ws[NC + c] = ssig;

    red[c] = bias[c];
    __syncthreads();
    if (c == 0) {
        double sb = 0.0;
        for (int i = 0; i < NC; ++i) sb += (double)red[i];
        ws[256] = (float)(sb / NC);
    }
    __syncthreads();
    red[c] = logf(ssig);
    __syncthreads();
    if (c == 0) {
        double sl = 0.0;
        for (int i = 0; i < NC; ++i) sl += (double)red[i];
        ws[257] = (float)((double)NB * (double)(NHW / 2) * sl);
    }
}

__global__ __launch_bounds__(256) void main_kernel(const float* __restrict__ x,
                                                   const float* __restrict__ ws,
                                                   const float* __restrict__ offp,
                                                   float* __restrict__ out,
                                                   float* __restrict__ partials) {
    __shared__ float4 pp[4][16];   // 1 KiB: per-wave pool partials

    const int tid  = threadIdx.x;
    const int j    = tid & 15;     // pixel-quad index: pixels l0 + 4j .. 4j+3
    const int cg   = tid >> 4;     // channel group 0..15 (8 channels each)
    const int wave = tid >> 6;
    const int lane = tid & 63;

    const int lt = blockIdx.x;     // l-tile 0..63
    const int b  = blockIdx.y;     // batch
    const int l0 = lt * LT;        // multiple of 64 (even)

    const size_t base = (size_t)b * (NC * NHW) + (size_t)(cg * 8) * NHW + l0 + j * 4;
    const float* __restrict__ xp = x + base;

    // ---- load 8 float4 into registers ----
    float4 v[8];
#pragma unroll
    for (int k = 0; k < 8; ++k)
        v[k] = *reinterpret_cast<const float4*>(xp + (size_t)k * NHW);

    // ---- per-thread pool partial over its 8 channels ----
    float4 acc = make_float4(0.f, 0.f, 0.f, 0.f);
#pragma unroll
    for (int k = 0; k < 8; ++k) {
        const int c = cg * 8 + k;
        const float wb = ws[c];
        if (c & 1) { acc.x += wb * v[k].x; acc.z += wb * v[k].z; }
        else       { acc.y += wb * v[k].y; acc.w += wb * v[k].w; }
    }

    // ---- reduce over the 4 channel-groups within this wave ----
#pragma unroll
    for (int off = 16; off <= 32; off <<= 1) {
        acc.x += __shfl_xor(acc.x, off);
        acc.y += __shfl_xor(acc.y, off);
        acc.z += __shfl_xor(acc.z, off);
        acc.w += __shfl_xor(acc.w, off);
    }
    if (lane < 16) pp[wave][j] = acc;   // lane==j for lane<16
    __syncthreads();

    // ---- final pool + gate (redundant per thread; VALU is idle) ----
    const float4 p0 = pp[0][j], p1 = pp[1][j], p2 = pp[2][j], p3 = pp[3][j];
    const float cst = ws[256] + offp[0];
    float4 g;
    g.x = 1.f / (1.f + __expf(-(p0.x + p1.x + p2.x + p3.x + cst))) + EPS;
    g.y = 1.f / (1.f + __expf(-(p0.y + p1.y + p2.y + p3.y + cst))) + EPS;
    g.z = 1.f / (1.f + __expf(-(p0.z + p1.z + p2.z + p3.z + cst))) + EPS;
    g.w = 1.f / (1.f + __expf(-(p0.w + p1.w + p2.w + p3.w + cst))) + EPS;

    // ---- per-block sum of log(g) over the 64 pixels (wave 0) ----
    if (wave == 0) {
        float slg = (lane < 16)
                  ? (__logf(g.x) + __logf(g.y) + __logf(g.z) + __logf(g.w))
                  : 0.f;
#pragma unroll
        for (int off = 32; off > 0; off >>= 1) slg += __shfl_down(slg, off);
        if (lane == 0) partials[b * gridDim.x + lt] = slg;
    }

    // ---- scale registers and store (NON-TEMPORAL: out is write-once) ----
    const float* __restrict__ ssig = ws + NC;
    float* __restrict__ op = out + base;
#pragma unroll
    for (int k = 0; k < 8; ++k) {
        const int c = cg * 8 + k;
        const float sc = ssig[c];
        f4 o;
        if (c & 1) { o.x = v[k].x * sc;  o.y = v[k].y * g.y;
                     o.z = v[k].z * sc;  o.w = v[k].w * g.w; }
        else       { o.x = v[k].x * g.x; o.y = v[k].y * sc;
                     o.z = v[k].z * g.z; o.w = v[k].w * sc; }
        __builtin_nontemporal_store(o, reinterpret_cast<f4*>(op + (size_t)k * NHW));
    }
}

__global__ __launch_bounds__(64) void fin_kernel(const float* __restrict__ partials,
                                                 const float* __restrict__ ws,
                                                 float* __restrict__ logdet,
                                                 int nlt) {
    const int b = blockIdx.x;
    const int t = threadIdx.x;  // 64 threads
    float v = (t < nlt) ? partials[b * nlt + t] : 0.f;
#pragma unroll
    for (int off = 32; off > 0; off >>= 1) v += __shfl_down(v, off);
    if (t == 0) logdet[b] = 64.f * v + ws[257];  // (C//2) = 64
}

extern "C" void kernel_launch(void* const* d_in, const int* in_sizes, int n_in,
                              void* d_out, int out_size, void* d_ws, size_t ws_size,
                              hipStream_t stream) {
    const float* x    = (const float*)d_in[0];
    const float* w    = (const float*)d_in[1];
    const float* bias = (const float*)d_in[2];
    const float* s    = (const float*)d_in[3];
    const float* offp = (const float*)d_in[4];

    float* out = (float*)d_out;
    float* logdet = out + (size_t)NB * NC * NHW;

    float* ws = (float*)d_ws;
    float* partials = ws + 512;

    const int nlt = NHW / LT;

    prep_kernel<<<1, 128, 0, stream>>>(w, bias, s, ws);
    main_kernel<<<dim3(nlt, NB), 256, 0, stream>>>(x, ws, offp, out, partials);
    fin_kernel<<<NB, 64, 0, stream>>>(partials, ws, logdet, nlt);
}